// Round 5
// baseline (302.496 us; speedup 1.0000x reference)
//
#include <hip/hip_runtime.h>
#include <hip/hip_bf16.h>

#define T_NUM 8192
#define D_DIM 1024
#define O_DIM 1024
#define E_NUM 8
#define CAP   8192
#define BM 256
#define BN 256
#define BK 64

typedef float  f32x4  __attribute__((ext_vector_type(4)));
typedef __bf16 bf16x8 __attribute__((ext_vector_type(8)));

__device__ __forceinline__ void gld_lds16(const void* g, void* l) {
  __builtin_amdgcn_global_load_lds(
      (__attribute__((address_space(1))) void*)(void*)(g),
      (__attribute__((address_space(3))) void*)(l), 16, 0, 0);
}

__device__ __forceinline__ unsigned short f2bf(float f) {
  __hip_bfloat16 h = __float2bfloat16(f);
  return __builtin_bit_cast(unsigned short, h);
}

// ---------------- fp32 -> bf16 conversion (for We) ----------------
__global__ __launch_bounds__(256) void cvt_kernel(const float* __restrict__ in,
                                                  ushort* __restrict__ out, int n4) {
  int i = blockIdx.x * 256 + threadIdx.x;
  if (i >= n4) return;
  float4 v = ((const float4*)in)[i];
  ushort4 r;
  r.x = f2bf(v.x); r.y = f2bf(v.y); r.z = f2bf(v.z); r.w = f2bf(v.w);
  ((ushort4*)out)[i] = r;
}

// ---------------- gating: logits, top-2, softmax, hierarchical scatter ----
__global__ __launch_bounds__(256) void gate_kernel(const float* __restrict__ x,
                                                   const float* __restrict__ Wg,
                                                   ushort* __restrict__ xb,
                                                   int* __restrict__ counts,
                                                   int* __restrict__ perm,
                                                   float* __restrict__ wgt) {
  __shared__ int   s_sel[64][2];
  __shared__ float s_w[64][2];
  __shared__ int   s_hist[E_NUM];
  __shared__ int   s_cursor[E_NUM];

  int tid  = threadIdx.x;
  int lane = tid & 63;
  int wv   = tid >> 6;
  if (tid < E_NUM) s_hist[tid] = 0;

  int t0 = blockIdx.x * 64;

  for (int it = 0; it < 16; ++it) {
    int tl = wv * 16 + it;
    int t  = t0 + tl;
    const float4* xv = (const float4*)(x + (long)t * D_DIM);
    ushort4* xo = (ushort4*)(xb + (long)t * D_DIM);

    float acc[E_NUM];
#pragma unroll
    for (int e = 0; e < E_NUM; ++e) acc[e] = 0.f;

#pragma unroll
    for (int i = 0; i < 4; ++i) {
      float4 xf = xv[lane + i * 64];
      ushort4 r;
      r.x = f2bf(xf.x); r.y = f2bf(xf.y); r.z = f2bf(xf.z); r.w = f2bf(xf.w);
      xo[lane + i * 64] = r;
#pragma unroll
      for (int e = 0; e < E_NUM; ++e) {
        const float4* wv4 = (const float4*)(Wg + e * D_DIM);
        float4 wf = wv4[lane + i * 64];
        acc[e] += xf.x * wf.x + xf.y * wf.y + xf.z * wf.z + xf.w * wf.w;
      }
    }

    float logit[E_NUM];
#pragma unroll
    for (int e = 0; e < E_NUM; ++e) {
      float v = acc[e];
      for (int off = 32; off > 0; off >>= 1) v += __shfl_down(v, off);
      logit[e] = v;                      // valid on lane 0
    }

    if (lane == 0) {
      int e0 = 0; float v0 = logit[0];
#pragma unroll
      for (int e = 1; e < E_NUM; ++e)
        if (logit[e] > v0) { v0 = logit[e]; e0 = e; }  // strict > : lowest idx wins
      int e1 = -1; float v1 = -1e30f;
#pragma unroll
      for (int e = 0; e < E_NUM; ++e) {
        if (e == e0) continue;
        if (logit[e] > v1) { v1 = logit[e]; e1 = e; }
      }
      float ex  = expf(v1 - v0);
      float den = 1.f + ex;
      s_sel[tl][0] = e0; s_w[tl][0] = 1.f / den;
      s_sel[tl][1] = e1; s_w[tl][1] = ex / den;
    }
  }
  __syncthreads();

  if (tid < 128) {
    int e = s_sel[tid >> 1][tid & 1];
    atomicAdd(&s_hist[e], 1);
  }
  __syncthreads();

  if (tid < E_NUM) s_cursor[tid] = atomicAdd(&counts[tid], s_hist[tid]);
  __syncthreads();

  if (tid < 128) {
    int tl = tid >> 1, k = tid & 1;
    int e  = s_sel[tl][k];
    int pos = atomicAdd(&s_cursor[e], 1);
    perm[e * CAP + pos] = t0 + tl;
    wgt [e * CAP + pos] = s_w[tl][k];
  }
}

// ---------------- grouped expert GEMM: 256x256 tile, BK=64, 8 waves ------
// grid = E * 32 * 4 = 1024 blocks, 512 threads. Blocks past count early-exit.
__global__ __launch_bounds__(512, 2) void moe_gemm(const __hip_bfloat16* __restrict__ xb,
                                                   const __hip_bfloat16* __restrict__ wb,
                                                   const float* __restrict__ be,
                                                   const int* __restrict__ counts,
                                                   const int* __restrict__ perm,
                                                   const float* __restrict__ wgt,
                                                   float* __restrict__ out) {
  int bid = blockIdx.x;
  int e  = bid >> 7;          // 128 blocks / expert
  int rt = (bid >> 2) & 31;
  int ct = bid & 3;
  int n = counts[e];
  if (n == 0 || rt * BM >= n) return;

  __shared__ __hip_bfloat16 lds_a[BM * BK];   // [256][64] row-major, 32KB
  __shared__ __hip_bfloat16 lds_b[BN * BK];   // [256][64] row-major, 32KB

  int tid  = threadIdx.x;
  int lane = tid & 63;
  int wid  = tid >> 6;
  int wm = wid >> 2, wn = wid & 3;           // 2 x 4 wave grid, each 128x64 out

  // staging geometry: thread covers (row = r*64 + tid>>3, 16B slot = tid&7)
  int srow  = tid >> 3;        // 0..63
  int slot8 = tid & 7;
  const int*   permE = perm + e * CAP;
  const float* wgtE  = wgt  + e * CAP;
  long tokA[4];
#pragma unroll
  for (int r = 0; r < 4; ++r) {
    int s = min(rt * BM + r * 64 + srow, n - 1);
    tokA[r] = permE[s];
  }
  const __hip_bfloat16* gB = wb + ((long)e * O_DIM + ct * BN) * D_DIM;

  f32x4 acc[8][4];
#pragma unroll
  for (int m = 0; m < 8; ++m)
#pragma unroll
    for (int nn = 0; nn < 4; ++nn) acc[m][nn] = (f32x4){0.f, 0.f, 0.f, 0.f};

  int lr = lane & 15;
  int lk = (lane >> 4) * 8;

  for (int k0 = 0; k0 < D_DIM; k0 += BK) {
    __syncthreads();                      // prev compute done before overwrite
#pragma unroll
    for (int r = 0; r < 4; ++r)
      gld_lds16(xb + tokA[r] * D_DIM + k0 + slot8 * 8,
                (char*)lds_a + r * 8192 + wid * 1024);
#pragma unroll
    for (int r = 0; r < 4; ++r)
      gld_lds16(gB + (long)(r * 64 + srow) * D_DIM + k0 + slot8 * 8,
                (char*)lds_b + r * 8192 + wid * 1024);
    __syncthreads();                      // drains vmcnt -> LDS ready

#pragma unroll
    for (int kk = 0; kk < 2; ++kk) {
      bf16x8 af[8], bf[4];
#pragma unroll
      for (int m = 0; m < 8; ++m)
        af[m] = *(const bf16x8*)(lds_a + (wm * 128 + m * 16 + lr) * BK + kk * 32 + lk);
#pragma unroll
      for (int nn = 0; nn < 4; ++nn)
        bf[nn] = *(const bf16x8*)(lds_b + (wn * 64 + nn * 16 + lr) * BK + kk * 32 + lk);
#pragma unroll
      for (int m = 0; m < 8; ++m)
#pragma unroll
        for (int nn = 0; nn < 4; ++nn)
          acc[m][nn] = __builtin_amdgcn_mfma_f32_16x16x32_bf16(af[m], bf[nn], acc[m][nn], 0, 0, 0);
    }
  }

  // epilogue: out[t, o] += w * (acc + be[e, o]) via fp32 atomics
  int base_m = rt * BM + wm * 128;
  int base_n = ct * BN + wn * 64;
  const float* beE = be + e * O_DIM;
#pragma unroll
  for (int m = 0; m < 8; ++m) {
#pragma unroll
    for (int r = 0; r < 4; ++r) {
      int s = base_m + m * 16 + (lane >> 4) * 4 + r;
      if (s < n) {
        long t  = permE[s];
        float w = wgtE[s];
        float* orow = out + t * O_DIM;
#pragma unroll
        for (int nn = 0; nn < 4; ++nn) {
          int o = base_n + nn * 16 + (lane & 15);
          atomicAdd(&orow[o], w * (acc[m][nn][r] + beE[o]));
        }
      }
    }
  }
}

extern "C" void kernel_launch(void* const* d_in, const int* in_sizes, int n_in,
                              void* d_out, int out_size, void* d_ws, size_t ws_size,
                              hipStream_t stream) {
  const float* x  = (const float*)d_in[0];   // [T, D]
  const float* Wg = (const float*)d_in[1];   // [E, D]
  const float* We = (const float*)d_in[2];   // [E, O, D]
  const float* be = (const float*)d_in[3];   // [E, O]
  float* out = (float*)d_out;                // [T, O]

  char* p = (char*)d_ws;
  __hip_bfloat16* xb = (__hip_bfloat16*)p;  p += (size_t)T_NUM * D_DIM * 2;
  __hip_bfloat16* wb = (__hip_bfloat16*)p;  p += (size_t)E_NUM * O_DIM * D_DIM * 2;
  int* counts = (int*)p;                    p += 256;
  int* perm   = (int*)p;                    p += (size_t)E_NUM * CAP * 4;
  float* wgt  = (float*)p;

  hipMemsetAsync(counts, 0, 256, stream);
  hipMemsetAsync(d_out, 0, (size_t)out_size * sizeof(float), stream);

  int n_w = E_NUM * O_DIM * D_DIM;  // 8388608
  cvt_kernel<<<n_w / 4 / 256, 256, 0, stream>>>(We, (ushort*)wb, n_w / 4);
  gate_kernel<<<T_NUM / 64, 256, 0, stream>>>(x, Wg, (ushort*)xb, counts, perm, wgt);
  moe_gemm<<<E_NUM * 32 * 4, 512, 0, stream>>>(xb, wb, be, counts, perm, wgt, out);
}

// Round 7
// 278.375 us; speedup vs baseline: 1.0867x; 1.0867x over previous
//
#include <hip/hip_runtime.h>
#include <hip/hip_bf16.h>

#define T_NUM 8192
#define D_DIM 1024
#define O_DIM 1024
#define E_NUM 8
#define CAP   8192
#define BM 256
#define BN 256
#define BK 64
#define NT (D_DIM / BK)   // 16 K-tiles

typedef float  f32x4  __attribute__((ext_vector_type(4)));
typedef __bf16 bf16x8 __attribute__((ext_vector_type(8)));

__device__ __forceinline__ void gld_lds16(const void* g, void* l) {
  __builtin_amdgcn_global_load_lds(
      (__attribute__((address_space(1))) void*)(void*)(g),
      (__attribute__((address_space(3))) void*)(l), 16, 0, 0);
}

__device__ __forceinline__ unsigned short f2bf(float f) {
  __hip_bfloat16 h = __float2bfloat16(f);
  return __builtin_bit_cast(unsigned short, h);
}

// ---------------- fp32 -> bf16 conversion (for We) ----------------
__global__ __launch_bounds__(256) void cvt_kernel(const float* __restrict__ in,
                                                  ushort* __restrict__ out, int n4) {
  int i = blockIdx.x * 256 + threadIdx.x;
  if (i >= n4) return;
  float4 v = ((const float4*)in)[i];
  ushort4 r;
  r.x = f2bf(v.x); r.y = f2bf(v.y); r.z = f2bf(v.z); r.w = f2bf(v.w);
  ((ushort4*)out)[i] = r;
}

// ---------------- gating: logits, top-2, softmax, hierarchical scatter ----
__global__ __launch_bounds__(256) void gate_kernel(const float* __restrict__ x,
                                                   const float* __restrict__ Wg,
                                                   ushort* __restrict__ xb,
                                                   int* __restrict__ counts,
                                                   int* __restrict__ perm,
                                                   float* __restrict__ wgt) {
  __shared__ int   s_sel[64][2];
  __shared__ float s_w[64][2];
  __shared__ int   s_hist[E_NUM];
  __shared__ int   s_cursor[E_NUM];

  int tid  = threadIdx.x;
  int lane = tid & 63;
  int wv   = tid >> 6;
  if (tid < E_NUM) s_hist[tid] = 0;

  int t0 = blockIdx.x * 64;

  for (int it = 0; it < 16; ++it) {
    int tl = wv * 16 + it;
    int t  = t0 + tl;
    const float4* xv = (const float4*)(x + (long)t * D_DIM);
    ushort4* xo = (ushort4*)(xb + (long)t * D_DIM);

    float acc[E_NUM];
#pragma unroll
    for (int e = 0; e < E_NUM; ++e) acc[e] = 0.f;

#pragma unroll
    for (int i = 0; i < 4; ++i) {
      float4 xf = xv[lane + i * 64];
      ushort4 r;
      r.x = f2bf(xf.x); r.y = f2bf(xf.y); r.z = f2bf(xf.z); r.w = f2bf(xf.w);
      xo[lane + i * 64] = r;
#pragma unroll
      for (int e = 0; e < E_NUM; ++e) {
        const float4* wv4 = (const float4*)(Wg + e * D_DIM);
        float4 wf = wv4[lane + i * 64];
        acc[e] += xf.x * wf.x + xf.y * wf.y + xf.z * wf.z + xf.w * wf.w;
      }
    }

    float logit[E_NUM];
#pragma unroll
    for (int e = 0; e < E_NUM; ++e) {
      float v = acc[e];
      for (int off = 32; off > 0; off >>= 1) v += __shfl_down(v, off);
      logit[e] = v;                      // valid on lane 0
    }

    if (lane == 0) {
      int e0 = 0; float v0 = logit[0];
#pragma unroll
      for (int e = 1; e < E_NUM; ++e)
        if (logit[e] > v0) { v0 = logit[e]; e0 = e; }  // strict > : lowest idx wins
      int e1 = -1; float v1 = -1e30f;
#pragma unroll
      for (int e = 0; e < E_NUM; ++e) {
        if (e == e0) continue;
        if (logit[e] > v1) { v1 = logit[e]; e1 = e; }
      }
      float ex  = expf(v1 - v0);
      float den = 1.f + ex;
      s_sel[tl][0] = e0; s_w[tl][0] = 1.f / den;
      s_sel[tl][1] = e1; s_w[tl][1] = ex / den;
    }
  }
  __syncthreads();

  if (tid < 128) {
    int e = s_sel[tid >> 1][tid & 1];
    atomicAdd(&s_hist[e], 1);
  }
  __syncthreads();

  if (tid < E_NUM) s_cursor[tid] = atomicAdd(&counts[tid], s_hist[tid]);
  __syncthreads();

  if (tid < 128) {
    int tl = tid >> 1, k = tid & 1;
    int e  = s_sel[tl][k];
    int pos = atomicAdd(&s_cursor[e], 1);
    perm[e * CAP + pos] = t0 + tl;
    wgt [e * CAP + pos] = s_w[tl][k];
  }
}

// ---- grouped expert GEMM: 256x256, BK=64, 8 waves, prefetch double-buffer
// grid = E * 32 * 4 = 1024 blocks, 512 threads. LDS 128KB -> 1 block/CU;
// prefetch (STAGE next tile before compute) hides HBM latency under MFMA.
__global__ __launch_bounds__(512, 2) void moe_gemm(const __hip_bfloat16* __restrict__ xb,
                                                   const __hip_bfloat16* __restrict__ wb,
                                                   const float* __restrict__ be,
                                                   const int* __restrict__ counts,
                                                   const int* __restrict__ perm,
                                                   const float* __restrict__ wgt,
                                                   float* __restrict__ out) {
  int bid = blockIdx.x;
  int e  = bid >> 7;          // 128 blocks / expert
  int rt = (bid >> 2) & 31;
  int ct = bid & 3;
  int n = counts[e];
  if (n == 0 || rt * BM >= n) return;

  // [2 buffers][A: 256x64 | B: 256x64] bf16, linear row-major, 128KB total
  __shared__ char lds[2 * 65536];

  int tid  = threadIdx.x;
  int lane = tid & 63;
  int wid  = tid >> 6;
  int wm = wid >> 2, wn = wid & 3;           // 2 x 4 wave grid, each 128x64 out

  int srow  = tid >> 3;        // 0..63
  int slot8 = tid & 7;
  const int*   permE = perm + e * CAP;
  const float* wgtE  = wgt  + e * CAP;
  long tokA[4];
#pragma unroll
  for (int r = 0; r < 4; ++r) {
    int s = min(rt * BM + r * 64 + srow, n - 1);
    tokA[r] = permE[s];
  }
  const __hip_bfloat16* gB = wb + ((long)e * O_DIM + ct * BN) * D_DIM;

  f32x4 acc[8][4];
#pragma unroll
  for (int m = 0; m < 8; ++m)
#pragma unroll
    for (int nn = 0; nn < 4; ++nn) acc[m][nn] = (f32x4){0.f, 0.f, 0.f, 0.f};

  int lr = lane & 15;
  int lk = (lane >> 4) * 8;

#define STAGE(buf, k0)                                                          \
  do {                                                                          \
    char* lA_ = lds + (buf) * 65536;                                            \
    char* lB_ = lds + (buf) * 65536 + 32768;                                    \
    _Pragma("unroll")                                                           \
    for (int r = 0; r < 4; ++r)                                                 \
      gld_lds16(xb + tokA[r] * D_DIM + (k0) + slot8 * 8,                        \
                lA_ + r * 8192 + wid * 1024);                                   \
    _Pragma("unroll")                                                           \
    for (int r = 0; r < 4; ++r)                                                 \
      gld_lds16(gB + (long)(r * 64 + srow) * D_DIM + (k0) + slot8 * 8,          \
                lB_ + r * 8192 + wid * 1024);                                   \
  } while (0)

#define COMPUTE(buf)                                                            \
  do {                                                                          \
    const __hip_bfloat16* la_ = (const __hip_bfloat16*)(lds + (buf) * 65536);   \
    const __hip_bfloat16* lb_ = (const __hip_bfloat16*)(lds + (buf) * 65536 + 32768); \
    _Pragma("unroll")                                                           \
    for (int kk = 0; kk < 2; ++kk) {                                            \
      bf16x8 af[8], bfv[4];                                                     \
      _Pragma("unroll")                                                         \
      for (int m = 0; m < 8; ++m)                                               \
        af[m] = *(const bf16x8*)(la_ + (wm * 128 + m * 16 + lr) * BK + kk * 32 + lk); \
      _Pragma("unroll")                                                         \
      for (int nn = 0; nn < 4; ++nn)                                            \
        bfv[nn] = *(const bf16x8*)(lb_ + (wn * 64 + nn * 16 + lr) * BK + kk * 32 + lk); \
      _Pragma("unroll")                                                         \
      for (int m = 0; m < 8; ++m)                                               \
        _Pragma("unroll")                                                       \
        for (int nn = 0; nn < 4; ++nn)                                          \
          acc[m][nn] = __builtin_amdgcn_mfma_f32_16x16x32_bf16(af[m], bfv[nn],  \
                                                               acc[m][nn], 0, 0, 0); \
    }                                                                           \
  } while (0)

  // prologue: fill buffer 0, drain, barrier
  STAGE(0, 0);
  __syncthreads();

  int cur = 0;
  for (int kt = 0; kt < NT - 1; ++kt) {
    STAGE(cur ^ 1, (kt + 1) * BK);   // issue next-tile loads FIRST (in flight
                                     // across the compute below)
    COMPUTE(cur);
    __syncthreads();                 // single vmcnt+lgkm drain per K-step
    cur ^= 1;
  }
  COMPUTE(cur);                      // epilogue tile, no prefetch

  // epilogue: out[t, o] += w * (acc + be[e, o]) via fp32 atomics
  int base_m = rt * BM + wm * 128;
  int base_n = ct * BN + wn * 64;
  const float* beE = be + e * O_DIM;
#pragma unroll
  for (int m = 0; m < 8; ++m) {
#pragma unroll
    for (int r = 0; r < 4; ++r) {
      int s = base_m + m * 16 + (lane >> 4) * 4 + r;
      if (s < n) {
        long t  = permE[s];
        float w = wgtE[s];
        float* orow = out + t * O_DIM;
#pragma unroll
        for (int nn = 0; nn < 4; ++nn) {
          int o = base_n + nn * 16 + (lane & 15);
          atomicAdd(&orow[o], w * (acc[m][nn][r] + beE[o]));
        }
      }
    }
  }
#undef STAGE
#undef COMPUTE
}

extern "C" void kernel_launch(void* const* d_in, const int* in_sizes, int n_in,
                              void* d_out, int out_size, void* d_ws, size_t ws_size,
                              hipStream_t stream) {
  const float* x  = (const float*)d_in[0];   // [T, D]
  const float* Wg = (const float*)d_in[1];   // [E, D]
  const float* We = (const float*)d_in[2];   // [E, O, D]
  const float* be = (const float*)d_in[3];   // [E, O]
  float* out = (float*)d_out;                // [T, O]

  char* p = (char*)d_ws;
  __hip_bfloat16* xb = (__hip_bfloat16*)p;  p += (size_t)T_NUM * D_DIM * 2;
  __hip_bfloat16* wb = (__hip_bfloat16*)p;  p += (size_t)E_NUM * O_DIM * D_DIM * 2;
  int* counts = (int*)p;                    p += 256;
  int* perm   = (int*)p;                    p += (size_t)E_NUM * CAP * 4;
  float* wgt  = (float*)p;

  hipMemsetAsync(counts, 0, 256, stream);
  hipMemsetAsync(d_out, 0, (size_t)out_size * sizeof(float), stream);

  int n_w = E_NUM * O_DIM * D_DIM;  // 8388608
  cvt_kernel<<<n_w / 4 / 256, 256, 0, stream>>>(We, (ushort*)wb, n_w / 4);
  gate_kernel<<<T_NUM / 64, 256, 0, stream>>>(x, Wg, (ushort*)xb, counts, perm, wgt);
  moe_gemm<<<E_NUM * 32 * 4, 512, 0, stream>>>(xb, wb, be, counts, perm, wgt, out);
}